// Round 17
// baseline (496.038 us; speedup 1.0000x reference)
//
#include <hip/hip_runtime.h>
#include <math.h>

#define NQ 4096
#define NK 16384
#define NROWS 20480
#define NCLS 100
#define PCLS 112        // padded class count (7 tiles of 16)
#define DCH 4           // key chunks in dist kernel (4096 keys each)

typedef __attribute__((ext_vector_type(8))) short bf16x8;
typedef __attribute__((ext_vector_type(4))) float f32x4;

__device__ inline unsigned short f2bf(float f) {
  unsigned u = __float_as_uint(f);
  u += 0x7fff + ((u >> 16) & 1);   // round to nearest even
  return (unsigned short)(u >> 16);
}
__device__ inline void upk(unsigned u, float& a, float& b) {
  a = __uint_as_float(u << 16);
  b = __uint_as_float(u & 0xffff0000u);
}
__device__ inline float fast_tanh(float x) {
  float e = __expf(2.f * x);
  return 1.f - 2.f / (e + 1.f);
}
__device__ inline void gload_lds16(const unsigned short* g, unsigned short* l) {
  __builtin_amdgcn_global_load_lds(
      (const __attribute__((address_space(1))) unsigned int*)g,
      (__attribute__((address_space(3))) unsigned int*)l, 16, 0, 0);
}

// ------- fused fp32->bf16 convert + column stats (ONE pass over x/xn) -----
// R17: grid (512, 2) = 1024 blocks (4/CU) -- R16's version ran only 128
// blocks and left half the CUs idle (parallelism regression masked the BW
// win). x-chunks of 8 rows, xn-chunks of 32 rows; per-thread loop 4/16
// float4 iterations. Partials: [seg][1024][2][512].
__global__ __launch_bounds__(256) void conv_stats(
    const float* __restrict__ x, const float* __restrict__ xn,
    unsigned short* __restrict__ outp, float* __restrict__ part) {
  int seg = blockIdx.y;
  int chunk = blockIdx.x;
  int rpc = seg ? (NK / 512) : (NQ / 512);
  const float* in = seg ? xn : x;
  unsigned short* out = outp + (seg ? (size_t)NQ * 512 : 0);
  int col4 = threadIdx.x & 127;       // float4-column 0..127 (512 cols)
  int rg = threadIdx.x >> 7;          // row-group 0/1
  int rowBase = chunk * rpc;
  float s[4] = {0.f, 0.f, 0.f, 0.f};
  float s2[4] = {0.f, 0.f, 0.f, 0.f};
  for (int r = rg; r < rpc; r += 2) {
    size_t row = rowBase + r;
    float4 v = ((const float4*)in)[row * 128 + col4];
    s[0] += v.x; s2[0] += v.x * v.x;
    s[1] += v.y; s2[1] += v.y * v.y;
    s[2] += v.z; s2[2] += v.z * v.z;
    s[3] += v.w; s2[3] += v.w * v.w;
    unsigned lo = (unsigned)f2bf(v.x) | ((unsigned)f2bf(v.y) << 16);
    unsigned hi = (unsigned)f2bf(v.z) | ((unsigned)f2bf(v.w) << 16);
    ((uint2*)out)[row * 128 + col4] = make_uint2(lo, hi);
  }
  float* p4 = part + ((size_t)seg * 1024 + chunk * 2 + rg) * 1024;
#pragma unroll
  for (int e = 0; e < 4; ++e) {
    p4[col4 * 4 + e] = s[e];
    p4[512 + col4 * 4 + e] = s2[e];
  }
}

// part -> alpha/beta for both segments in ONE dispatch (1024 partials now)
__global__ __launch_bounds__(256) void finish_ab2(
    const float* __restrict__ part,
    const float* __restrict__ g, const float* __restrict__ bt,
    float* __restrict__ abq, float* __restrict__ abk) {
  int j = blockIdx.x * 256 + threadIdx.x;
  int seg = blockIdx.y;
  const float* p4 = part + (size_t)seg * 1024 * 1024;
  float invN = seg ? (1.0f / NK) : (1.0f / NQ);
  float* ab = seg ? abk : abq;
  float s = 0.f, s2 = 0.f;
  for (int c = 0; c < 1024; ++c) {
    s += p4[(size_t)c * 1024 + j];
    s2 += p4[(size_t)c * 1024 + 512 + j];
  }
  float m = s * invN;
  float v = fmaxf(s2 * invN - m * m, 0.f);
  float a = g[j] * rsqrtf(v + 1e-5f);
  ab[2 * j] = a;
  ab[2 * j + 1] = bt[j] - a * m;
}

// atomic (s1,s2) -> alpha/beta, q and k in ONE dispatch (grid.y selects)
__global__ __launch_bounds__(256) void ab_from_stats2(
    const float* __restrict__ stq, const float* __restrict__ stk,
    const float* __restrict__ g, const float* __restrict__ bt,
    float* __restrict__ abq, float* __restrict__ abk, int M) {
  int j = blockIdx.x * 256 + threadIdx.x;
  if (j >= M) return;
  int seg = blockIdx.y;
  const float* st = seg ? stk : stq;
  float invN = seg ? (1.0f / NK) : (1.0f / NQ);
  float* ab = seg ? abk : abq;
  float s = st[2 * j], s2 = st[2 * j + 1];
  float m = s * invN;
  float v = fmaxf(s2 * invN - m * m, 0.f);
  float a = g[j] * rsqrtf(v + 1e-5f);
  ab[2 * j] = a;
  ab[2 * j + 1] = bt[j] - a * m;
}

// ---------------- fold BN into weights: q AND k in one pass ---------------
// Reads W once, writes both wq/wk. For layers >=1 computes ab INLINE from
// the previous gemm's stats. Blocks 0,1 zero the CURRENT layer's stat
// buffers (ping-pong pair, distinct from the stats being read).
__global__ __launch_bounds__(256) void fold_w2(
    const float* __restrict__ W, const float* __restrict__ b,
    const float* __restrict__ abq, const float* __restrict__ abk,   // lyr 0
    const float* __restrict__ stq, const float* __restrict__ stk,   // lyr >=1
    const float* __restrict__ g, const float* __restrict__ bt,      // prev BN
    int K,
    unsigned short* __restrict__ Woq, unsigned short* __restrict__ Wok,
    float* __restrict__ boq, float* __restrict__ bok,
    float* __restrict__ statzq, float* __restrict__ statzk, int M,
    int useStats) {
  int j = blockIdx.x;
  int t = threadIdx.x;
  if (j == 0) for (int i = t; i < 2 * M; i += 256) statzq[i] = 0.f;
  if (j == 1) for (int i = t; i < 2 * M; i += 256) statzk[i] = 0.f;
  const float* Wr = W + (size_t)j * K;
  unsigned short* Wq = Woq + (size_t)j * K;
  unsigned short* Wk = Wok + (size_t)j * K;
  float sq = 0.f, sk = 0.f;
  for (int k = t; k < K; k += 256) {
    float w = Wr[k];
    float aq, bq_, ak, bk_;
    if (useStats) {
      float s = stq[2 * k], s2 = stq[2 * k + 1];
      float m = s * (1.0f / NQ);
      float v = fmaxf(s2 * (1.0f / NQ) - m * m, 0.f);
      aq = g[k] * rsqrtf(v + 1e-5f);
      bq_ = bt[k] - aq * m;
      s = stk[2 * k]; s2 = stk[2 * k + 1];
      m = s * (1.0f / NK);
      v = fmaxf(s2 * (1.0f / NK) - m * m, 0.f);
      ak = g[k] * rsqrtf(v + 1e-5f);
      bk_ = bt[k] - ak * m;
    } else {
      aq = abq[2 * k]; bq_ = abq[2 * k + 1];
      ak = abk[2 * k]; bk_ = abk[2 * k + 1];
    }
    Wq[k] = f2bf(aq * w);
    Wk[k] = f2bf(ak * w);
    sq += bq_ * w;
    sk += bk_ * w;
  }
  __shared__ float redq[4], redk[4];
#pragma unroll
  for (int off = 32; off; off >>= 1) {
    sq += __shfl_down(sq, off, 64);
    sk += __shfl_down(sk, off, 64);
  }
  if ((t & 63) == 0) { redq[t >> 6] = sq; redk[t >> 6] = sk; }
  __syncthreads();
  if (t == 0) {
    boq[j] = b[j] + redq[0] + redq[1] + redq[2] + redq[3];
    bok[j] = b[j] + redk[0] + redk[1] + redk[2] + redk[3];
  }
}

// ---------------- merged q/k MFMA GEMM, BK=32, 4-buffer (R4 schedule) -----
// XCD row-clustering swizzle (R13, kept): each XCD owns whole A-row-tiles.
__global__ __launch_bounds__(256) void gemm_v8(
    const unsigned short* __restrict__ A,
    const unsigned short* __restrict__ Wq, const unsigned short* __restrict__ Wk,
    const float* __restrict__ bq, const float* __restrict__ bk,
    unsigned short* __restrict__ C,
    float* __restrict__ stq, float* __restrict__ stk, int M, int K) {
  __shared__ unsigned short As[4][128 * 32];
  __shared__ unsigned short Ws[4][128 * 32];
  int tid = threadIdx.x;
  int l = tid & 63, w = tid >> 6;
  int nx = gridDim.x;
  int lin = blockIdx.y * nx + blockIdx.x;
  int xcd = lin & 7, j = lin >> 3;
  int rowB = (j / nx) * 8 + xcd;     // each XCD: rows {xcd, xcd+8, ...}
  int colB = j % nx;
  int rowBase = rowB * 128, colBase = colB * 128;
  int seg = rowBase >= NQ;
  const unsigned short* W = seg ? Wk : Wq;
  const float* bias = seg ? bk : bq;
  float* st = seg ? stk : stq;
  int rowOff = (w >> 1) * 64, colOff = (w & 1) * 64;
  int fr = l & 15, fc = l >> 4;

  const unsigned short* Ag[2];
  const unsigned short* Wg[2];
  int slot[2];
#pragma unroll
  for (int jj = 0; jj < 2; ++jj) {
    int i = tid + jj * 256;
    int r = i >> 2, c = (i & 3) ^ (r & 3);
    slot[jj] = i * 8;
    Ag[jj] = A + (size_t)(rowBase + r) * K + c * 8;
    Wg[jj] = W + (size_t)(colBase + r) * K + c * 8;
  }
  auto stage = [&](int s, int bb) {
    int ko = s * 32;
#pragma unroll
    for (int jj = 0; jj < 2; ++jj) {
      gload_lds16(Ag[jj] + ko, &As[bb][0] + slot[jj]);
      gload_lds16(Wg[jj] + ko, &Ws[bb][0] + slot[jj]);
    }
  };

  f32x4 acc[4][4];
#pragma unroll
  for (int m = 0; m < 4; ++m)
#pragma unroll
    for (int n = 0; n < 4; ++n) acc[m][n] = (f32x4){0.f, 0.f, 0.f, 0.f};

  int NS = K >> 5;   // 16 or 32 slices
  stage(0, 0);
  stage(1, 1);
  stage(2, 2);
  for (int s = 0; s < NS; ++s) {
    if (s + 2 < NS) {
      asm volatile("s_waitcnt vmcnt(8)" ::: "memory");
    } else if (s + 1 < NS) {
      asm volatile("s_waitcnt vmcnt(4)" ::: "memory");
    } else {
      asm volatile("s_waitcnt vmcnt(0)" ::: "memory");
    }
    __builtin_amdgcn_s_barrier();
    __builtin_amdgcn_sched_barrier(0);
    int b = s & 3;
    bf16x8 av[4], bv[4];
#pragma unroll
    for (int m = 0; m < 4; ++m) {
      int row = rowOff + m * 16 + fr;
      int p = fc ^ (row & 3);
      av[m] = *(const bf16x8*)((const char*)&As[b][0] + row * 64 + p * 16);
    }
#pragma unroll
    for (int n = 0; n < 4; ++n) {
      int row = colOff + n * 16 + fr;
      int p = fc ^ (row & 3);
      bv[n] = *(const bf16x8*)((const char*)&Ws[b][0] + row * 64 + p * 16);
    }
    if (s + 3 < NS) stage(s + 3, (s + 3) & 3);
#pragma unroll
    for (int m = 0; m < 4; ++m)
#pragma unroll
      for (int n = 0; n < 4; ++n)
        acc[m][n] = __builtin_amdgcn_mfma_f32_16x16x32_bf16(av[m], bv[n], acc[m][n], 0, 0, 0);
  }

  float ts1[4] = {0.f, 0.f, 0.f, 0.f};
  float ts2[4] = {0.f, 0.f, 0.f, 0.f};
#pragma unroll
  for (int m = 0; m < 4; ++m) {
#pragma unroll
    for (int r = 0; r < 4; ++r) {
      size_t row = rowBase + rowOff + m * 16 + fc * 4 + r;
      unsigned short* Crow = C + row * M;
#pragma unroll
      for (int n = 0; n < 4; ++n) {
        int col = colBase + colOff + n * 16 + fr;
        float val = fast_tanh(acc[m][n][r] + bias[col]);
        Crow[col] = f2bf(val);
        ts1[n] += val;
        ts2[n] += val * val;
      }
    }
  }
#pragma unroll
  for (int n = 0; n < 4; ++n) {
    float s1 = ts1[n], s2 = ts2[n];
    s1 += __shfl_xor(s1, 16, 64); s1 += __shfl_xor(s1, 32, 64);
    s2 += __shfl_xor(s2, 16, 64); s2 += __shfl_xor(s2, 32, 64);
    if (fc == 0) {
      int col = colBase + colOff + n * 16 + fr;
      atomicAdd(&st[2 * col], s1);
      atomicAdd(&st[2 * col + 1], s2);
    }
  }
}

// ---------------- final BN apply + row norms, q and k in ONE dispatch -----
__global__ __launch_bounds__(256) void bn_final2(
    unsigned short* __restrict__ F, const float* __restrict__ abq,
    const float* __restrict__ abk, float* __restrict__ norms) {
  int w = threadIdx.x >> 6, l = threadIdx.x & 63;
  int row = blockIdx.x * 4 + w;
  const float* ab = (row < NQ) ? abq : abk;
  unsigned short* p = F + (size_t)row * 512 + l * 8;
  uint4 v = *(const uint4*)p;
  int j0 = l * 8;
  float f[8];
  upk(v.x, f[0], f[1]); upk(v.y, f[2], f[3]);
  upk(v.z, f[4], f[5]); upk(v.w, f[6], f[7]);
  float s = 0.f;
  unsigned pk[4];
#pragma unroll
  for (int e = 0; e < 8; e += 2) {
    float a0 = ab[2 * (j0 + e)] * f[e] + ab[2 * (j0 + e) + 1];
    float a1 = ab[2 * (j0 + e + 1)] * f[e + 1] + ab[2 * (j0 + e + 1) + 1];
    s += a0 * a0 + a1 * a1;
    pk[e >> 1] = (unsigned)f2bf(a0) | ((unsigned)f2bf(a1) << 16);
  }
  *(uint4*)p = make_uint4(pk[0], pk[1], pk[2], pk[3]);
#pragma unroll
  for (int off = 32; off; off >>= 1) s += __shfl_down(s, off, 64);
  if (l == 0) norms[row] = s;
}

// ---------------- OHE^T scatter: oheT[cls][key] = 1.0bf ----------------
__global__ __launch_bounds__(256) void scatter_ohe(
    const int* __restrict__ yn, unsigned short* __restrict__ oheT) {
  int k = blockIdx.x * 256 + threadIdx.x;
  if (k < NK) oheT[(size_t)yn[k] * NK + k] = 0x3F80;   // bf16 1.0
}

// ---------------- distance + exp + class-sum via double MFMA ---------------
// R15's proven core (260us, DCH=4): byte-identical.
__global__ __launch_bounds__(512, 2) void dist_v5(
    const unsigned short* __restrict__ F,   // [20480,512]; Q rows 0.., K rows 4096..
    const float* __restrict__ norms,        // [20480]
    const unsigned short* __restrict__ oheT,// [PCLS][NK] bf16
    float* __restrict__ part) {             // [NQ][DCH][PCLS]
  __shared__ unsigned short kbuf[3][128 * 64];   // 3 x 16KB, XOR-swizzled rows
  __shared__ unsigned short Qs[8 * 64 * 64];     // 64KB Q tile, 8 subtiles, swz
  __shared__ unsigned short Ps[64][136];         // P tile [q][key], pad 8
  __shared__ float k2s[4096];                    // 16KB: chunk key norms
  int tid = threadIdx.x;
  int l = tid & 63, w = tid >> 6;
  int qBase = blockIdx.x * 64;
  int kBase0 = blockIdx.y * 4096;
  int mg = w & 1, ng = w >> 1;          // main: q-half, key-quarter
  int qtw = w & 3, cth = w >> 2;        // mini: q-tile, cls-half
  int fr = l & 15, fc = l >> 4;

  for (int i = tid; i < 4096; i += 512) k2s[i] = norms[NQ + kBase0 + i];
  float q2r0 = norms[qBase + mg * 32 + fr];
  float q2r1 = norms[qBase + mg * 32 + 16 + fr];
  __builtin_amdgcn_sched_barrier(0);

  // Q tile -> LDS, 8 subtiles of [64 rows][64 cols], 128B row stride.
#pragma unroll
  for (int j = 0; j < 8; ++j) {
    int i = tid + j * 512;
    int ss = i >> 9;
    int row = (i >> 3) & 63;
    int c = (i & 7) ^ (row & 7);
    gload_lds16(F + (size_t)(qBase + row) * 512 + ss * 64 + c * 8, Qs + i * 8);
  }

  int i0 = tid, i1 = tid + 512;
  int r0 = i0 >> 3, c0 = (i0 & 7) ^ (r0 & 7);
  int r1 = i1 >> 3, c1 = (i1 & 7) ^ (r1 & 7);
  auto stage = [&](int slice, int bb) {   // slice 0..255 over the 4096-key chunk
    int kRow = kBase0 + (slice >> 3) * 128;
    int ko = (slice & 7) * 64;
    gload_lds16(F + (size_t)(NQ + kRow + r0) * 512 + ko + c0 * 8,
                &kbuf[bb][0] + i0 * 8);
    gload_lds16(F + (size_t)(NQ + kRow + r1) * 512 + ko + c1 * 8,
                &kbuf[bb][0] + i1 * 8);
  };

  f32x4 accC[4];
#pragma unroll
  for (int c = 0; c < 4; ++c) accC[c] = (f32x4){0.f, 0.f, 0.f, 0.f};

  stage(0, 0);
  stage(1, 1);
  asm volatile("s_waitcnt lgkmcnt(0)" ::: "memory");  // k2s ds_writes done

  for (int kt = 0; kt < 32; ++kt) {
    f32x4 acc[2][2];   // [key-16-tile][q-tile]
#pragma unroll
    for (int t2 = 0; t2 < 2; ++t2)
#pragma unroll
      for (int qt = 0; qt < 2; ++qt) acc[t2][qt] = (f32x4){0.f, 0.f, 0.f, 0.f};
    bf16x8 ob[4][4];   // per-kt OHE fragments, prefetched at s==0
#pragma unroll
    for (int kc = 0; kc < 4; ++kc)
#pragma unroll
      for (int c = 0; c < 4; ++c) ob[kc][c] = (bf16x8){0, 0, 0, 0, 0, 0, 0, 0};
#pragma unroll
    for (int s = 0; s < 8; ++s) {
      int slice = kt * 8 + s;
      // Queue model (issue order pinned by sched_barriers):
      //   s==0: [st(s)] [st(s+1)] (+Q(8) at kt==0)       -> vmcnt(2)
      //   s==1: [st(s)] [st(s+1)] [ob(16)]               -> vmcnt(18)
      //   s==2: [st(s)] [ob(16)] [st(s+1)]               -> vmcnt(18)
      //   s>=3: [ob?(done)] [st(s)] [st(s+1)]            -> vmcnt(2)
      //   slice==255: only [st(255)] outstanding         -> vmcnt(0)
      if (slice == 255) {
        asm volatile("s_waitcnt vmcnt(0)" ::: "memory");
      } else if (s == 1 || s == 2) {
        asm volatile("s_waitcnt vmcnt(18)" ::: "memory");
      } else {
        asm volatile("s_waitcnt vmcnt(2)" ::: "memory");
      }
      __builtin_amdgcn_s_barrier();
      __builtin_amdgcn_sched_barrier(0);  // pin issues below the barrier
      int b = slice % 3;
      bf16x8 kv[2][2];
#pragma unroll
      for (int kc = 0; kc < 2; ++kc)
#pragma unroll
        for (int t2 = 0; t2 < 2; ++t2) {
          int row = ng * 32 + t2 * 16 + fr;
          int sl = (kc * 4 + fc) ^ (row & 7);
          kv[kc][t2] = *(const bf16x8*)((const char*)&kbuf[b][0] + row * 128 + sl * 16);
        }
      bf16x8 avx[2][2];  // [kc][qt] Q fragments from LDS subtile s
#pragma unroll
      for (int kc = 0; kc < 2; ++kc)
#pragma unroll
        for (int qt = 0; qt < 2; ++qt) {
          int row = mg * 32 + qt * 16 + fr;
          int sl = (kc * 4 + fc) ^ (fr & 7);
          avx[kc][qt] = *(const bf16x8*)((const char*)Qs + s * 8192 + row * 128 + sl * 16);
        }
      if (slice + 2 < 256) stage(slice + 2, (slice + 2) % 3);
      if (s == 0) {
        __builtin_amdgcn_sched_barrier(0);  // keep ob issue after stage pair
#pragma unroll
        for (int kc = 0; kc < 4; ++kc)
#pragma unroll
          for (int c = 0; c < 4; ++c) {
            int ctg = cth * 4 + c;
            if (ctg < 7)
              ob[kc][c] = *(const bf16x8*)(
                  oheT + (size_t)(ctg * 16 + fr) * NK + kBase0 + kt * 128 + kc * 32 + fc * 8);
          }
        __builtin_amdgcn_sched_barrier(0);
      }
#pragma unroll
      for (int kc = 0; kc < 2; ++kc)
#pragma unroll
        for (int t2 = 0; t2 < 2; ++t2)
#pragma unroll
          for (int qt = 0; qt < 2; ++qt)
            acc[t2][qt] = __builtin_amdgcn_mfma_f32_16x16x32_bf16(
                kv[kc][t2], avx[kc][qt], acc[t2][qt], 0, 0, 0);
    }
    // ---- epilogue: p = exp(-dist) -> bf16 -> Ps[q][key] ----
#pragma unroll
    for (int t2 = 0; t2 < 2; ++t2) {
      float k2v[4];
#pragma unroll
      for (int r = 0; r < 4; ++r)
        k2v[r] = k2s[kt * 128 + ng * 32 + t2 * 16 + fc * 4 + r];
#pragma unroll
      for (int qt = 0; qt < 2; ++qt) {
        int q = mg * 32 + qt * 16 + fr;
        float q2 = qt ? q2r1 : q2r0;
        float pv[4];
#pragma unroll
        for (int r = 0; r < 4; ++r) {
          float d2 = q2 + k2v[r] - 2.f * acc[t2][qt][r];
          pv[r] = __expf(-sqrtf(fmaxf(d2, 0.f)));
        }
        unsigned lo = (unsigned)f2bf(pv[0]) | ((unsigned)f2bf(pv[1]) << 16);
        unsigned hi = (unsigned)f2bf(pv[2]) | ((unsigned)f2bf(pv[3]) << 16);
        *(uint2*)(&Ps[q][ng * 32 + t2 * 16 + fc * 4]) = make_uint2(lo, hi);
      }
    }
    asm volatile("s_waitcnt lgkmcnt(0)" ::: "memory");
    __builtin_amdgcn_s_barrier();
    __builtin_amdgcn_sched_barrier(0);
    // ---- mini-GEMM: accC[q][cls] += P[q][k] * OHE[k][cls] (ob pre-loaded) --
#pragma unroll
    for (int kc = 0; kc < 4; ++kc) {
      bf16x8 pa = *(const bf16x8*)(&Ps[qtw * 16 + fr][kc * 32 + fc * 8]);
#pragma unroll
      for (int c = 0; c < 4; ++c) {
        int ctg = cth * 4 + c;
        if (ctg < 7)
          accC[c] = __builtin_amdgcn_mfma_f32_16x16x32_bf16(pa, ob[kc][c], accC[c], 0, 0, 0);
      }
    }
  }
  // ---- write per-chunk class sums ----
#pragma unroll
  for (int c = 0; c < 4; ++c) {
    int ctg = cth * 4 + c;
    if (ctg < 7) {
#pragma unroll
      for (int r = 0; r < 4; ++r) {
        int q = qBase + qtw * 16 + fc * 4 + r;
        part[((size_t)q * DCH + blockIdx.y) * PCLS + ctg * 16 + fr] = accC[c][r];
      }
    }
  }
}

// ---------------- combine partials -> clipped scores ----------------
__global__ __launch_bounds__(128) void combine_out(
    const float* __restrict__ part, float* __restrict__ outp) {
  int q = blockIdx.x;
  int t = threadIdx.x;
  float num = 0.f;
  if (t < NCLS) {
#pragma unroll
    for (int ch = 0; ch < DCH; ++ch)
      num += part[((size_t)q * DCH + ch) * PCLS + t];
  }
  __shared__ float sn[128];
  sn[t] = (t < NCLS) ? num : 0.f;
  __syncthreads();
#pragma unroll
  for (int off = 64; off; off >>= 1) {
    if (t < off) sn[t] += sn[t + off];
    __syncthreads();
  }
  float L = sn[0];
  if (t < NCLS) outp[(size_t)q * NCLS + t] = fminf(fmaxf(num / L, 0.f), 1.f);
}

// ---------------- host orchestration ----------------
extern "C" void kernel_launch(void* const* d_in, const int* in_sizes, int n_in,
                              void* d_out, int out_size, void* d_ws, size_t ws_size,
                              hipStream_t stream) {
  (void)in_sizes; (void)n_in; (void)out_size; (void)ws_size;
  const float* x   = (const float*)d_in[0];
  const float* xn  = (const float*)d_in[1];
  const int*   yn  = (const int*)d_in[2];
  const float* ing = (const float*)d_in[3];
  const float* inb = (const float*)d_in[4];
  const float* Wl[3]  = {(const float*)d_in[5], (const float*)d_in[9],  (const float*)d_in[13]};
  const float* bl[3]  = {(const float*)d_in[6], (const float*)d_in[10], (const float*)d_in[14]};
  const float* gl[3]  = {(const float*)d_in[7], (const float*)d_in[11], (const float*)d_in[15]};
  const float* btl[3] = {(const float*)d_in[8], (const float*)d_in[12], (const float*)d_in[16]};
  float* outp = (float*)d_out;

  unsigned short* featA = (unsigned short*)d_ws;                 // 20480*1024 bf16
  unsigned short* featB = featA + (size_t)NROWS * 1024;
  unsigned short* wq  = featB + (size_t)NROWS * 1024;            // 1024*1024 bf16
  unsigned short* wk  = wq + (size_t)1024 * 1024;                // 1024*1024 bf16
  unsigned short* ohe = wk + (size_t)1024 * 1024;                // PCLS*NK bf16
  float* spart = (float*)(ohe + (size_t)PCLS * NK);              // 2*1024*1024
  float* abq   = spart + 2 * 1024 * 1024;                        // 2048
  float* abk   = abq + 2048;                                     // 2048
  float* stAq  = abk + 2048;                                     // 2048
  float* stAk  = stAq + 2048;                                    // 2048
  float* stBq  = stAk + 2048;                                    // 2048
  float* stBk  = stBq + 2048;                                    // 2048
  float* bpq   = stBk + 2048;                                    // 1024
  float* bpk   = bpq + 1024;                                     // 1024
  float* norms = bpk + 1024;                                     // 20480
  float* part  = norms + NROWS;                                  // NQ*DCH*PCLS

  // fused fp32->bf16 + column stats: ONE pass over x/xn, 1024 blocks
  conv_stats<<<dim3(512, 2), 256, 0, stream>>>(x, xn, featA, spart);
  finish_ab2<<<dim3(2, 2), 256, 0, stream>>>(spart, ing, inb, abq, abk);

  // one-hot transpose for the class mini-GEMM
  hipMemsetAsync(ohe, 0, (size_t)PCLS * NK * sizeof(unsigned short), stream);
  scatter_ohe<<<NK / 256, 256, 0, stream>>>(yn, ohe);

  int dims[4] = {512, 1024, 1024, 512};
  unsigned short *src = featA, *dst = featB;
  for (int lyr = 0; lyr < 3; ++lyr) {
    int K = dims[lyr], M = dims[lyr + 1];
    // ping-pong stat buffers: layer lyr accumulates into cur, fold reads prev
    float* curQ = (lyr & 1) ? stBq : stAq;
    float* curK = (lyr & 1) ? stBk : stAk;
    float* prevQ = (lyr & 1) ? stAq : stBq;
    float* prevK = (lyr & 1) ? stAk : stBk;
    // fold q+k in one pass; for lyr>=1 computes ab inline from prev stats
    fold_w2<<<M, 256, 0, stream>>>(
        Wl[lyr], bl[lyr], abq, abk, prevQ, prevK,
        lyr ? gl[lyr - 1] : ing, lyr ? btl[lyr - 1] : inb,
        K, wq, wk, bpq, bpk, curQ, curK, M, lyr > 0);
    // merged q+k GEMM: rows 0..NQ-1 use wq/bpq/statq, rest wk/bpk/statk
    gemm_v8<<<dim3(M / 128, NROWS / 128), 256, 0, stream>>>(
        src, wq, wk, bpq, bpk, dst, curQ, curK, M, K);
    unsigned short* t = src; src = dst; dst = t;
  }
  // final ab (layer-2 stats live in the lyr=2 'cur' pair = stA)
  ab_from_stats2<<<dim3(2, 2), 256, 0, stream>>>(
      stAq, stAk, gl[2], btl[2], abq, abk, 512);
  // final BN + row norms for all 20480 rows (1 dispatch)
  bn_final2<<<NROWS / 4, 256, 0, stream>>>(src, abq, abk, norms);

  dist_v5<<<dim3(NQ / 64, DCH), 512, 0, stream>>>(src, norms, ohe, part);
  combine_out<<<NQ, 128, 0, stream>>>(part, outp);
}

// Round 18
// 474.810 us; speedup vs baseline: 1.0447x; 1.0447x over previous
//
#include <hip/hip_runtime.h>
#include <math.h>

#define NQ 4096
#define NK 16384
#define NROWS 20480
#define NCLS 100
#define PCLS 112        // padded class count (7 tiles of 16)
#define DCH 4           // key chunks in dist kernel (4096 keys each)

typedef __attribute__((ext_vector_type(8))) short bf16x8;
typedef __attribute__((ext_vector_type(4))) float f32x4;

__device__ inline unsigned short f2bf(float f) {
  unsigned u = __float_as_uint(f);
  u += 0x7fff + ((u >> 16) & 1);   // round to nearest even
  return (unsigned short)(u >> 16);
}
__device__ inline void upk(unsigned u, float& a, float& b) {
  a = __uint_as_float(u << 16);
  b = __uint_as_float(u & 0xffff0000u);
}
__device__ inline float fast_tanh(float x) {
  float e = __expf(2.f * x);
  return 1.f - 2.f / (e + 1.f);
}
__device__ inline void gload_lds16(const unsigned short* g, unsigned short* l) {
  __builtin_amdgcn_global_load_lds(
      (const __attribute__((address_space(1))) unsigned int*)g,
      (__attribute__((address_space(3))) unsigned int*)l, 16, 0, 0);
}

// ---------------- fp32 -> bf16 convert, x and xn in ONE dispatch ----------
__global__ __launch_bounds__(256) void conv2_bf16(
    const float* __restrict__ x, const float* __restrict__ xn,
    unsigned short* __restrict__ outp) {
  const size_t n4q = (size_t)NQ * 512 / 4;
  const size_t n4 = (size_t)NROWS * 512 / 4;
  size_t i = (size_t)blockIdx.x * 256 + threadIdx.x;
  size_t stride = (size_t)gridDim.x * 256;
  for (; i < n4; i += stride) {
    float4 v = (i < n4q) ? ((const float4*)x)[i] : ((const float4*)xn)[i - n4q];
    unsigned lo = (unsigned)f2bf(v.x) | ((unsigned)f2bf(v.y) << 16);
    unsigned hi = (unsigned)f2bf(v.z) | ((unsigned)f2bf(v.w) << 16);
    ((uint2*)outp)[i] = make_uint2(lo, hi);
  }
}

// ---------------- column stats over rows, x and xn in ONE dispatch --------
__global__ __launch_bounds__(256) void colstats2(
    const float* __restrict__ x, const float* __restrict__ xn,
    float* __restrict__ part) {   // [2][64][2][512]
  int j = blockIdx.x * 256 + threadIdx.x;
  int c = blockIdx.y;
  int seg = blockIdx.z;
  const float* A = seg ? xn : x;
  int rpc = seg ? (NK / 64) : (NQ / 64);
  float* p4 = part + (size_t)seg * 64 * 2 * 512;
  const float* p = A + (size_t)c * rpc * 512 + j;
  float s = 0.f, s2 = 0.f;
#pragma unroll 4
  for (int r = 0; r < rpc; ++r) {
    float v = p[(size_t)r * 512];
    s += v; s2 += v * v;
  }
  p4[(size_t)c * 2 * 512 + j] = s;
  p4[(size_t)c * 2 * 512 + 512 + j] = s2;
}

// part -> alpha/beta for both segments in ONE dispatch
__global__ __launch_bounds__(256) void finish_ab2(
    const float* __restrict__ part,
    const float* __restrict__ g, const float* __restrict__ bt,
    float* __restrict__ abq, float* __restrict__ abk) {
  int j = blockIdx.x * 256 + threadIdx.x;
  int seg = blockIdx.y;
  const float* p4 = part + (size_t)seg * 64 * 2 * 512;
  float invN = seg ? (1.0f / NK) : (1.0f / NQ);
  float* ab = seg ? abk : abq;
  float s = 0.f, s2 = 0.f;
  for (int c = 0; c < 64; ++c) {
    s += p4[(size_t)c * 2 * 512 + j];
    s2 += p4[(size_t)c * 2 * 512 + 512 + j];
  }
  float m = s * invN;
  float v = fmaxf(s2 * invN - m * m, 0.f);
  float a = g[j] * rsqrtf(v + 1e-5f);
  ab[2 * j] = a;
  ab[2 * j + 1] = bt[j] - a * m;
}

// atomic (s1,s2) -> alpha/beta, q and k in ONE dispatch (grid.y selects)
__global__ __launch_bounds__(256) void ab_from_stats2(
    const float* __restrict__ stq, const float* __restrict__ stk,
    const float* __restrict__ g, const float* __restrict__ bt,
    float* __restrict__ abq, float* __restrict__ abk, int M) {
  int j = blockIdx.x * 256 + threadIdx.x;
  if (j >= M) return;
  int seg = blockIdx.y;
  const float* st = seg ? stk : stq;
  float invN = seg ? (1.0f / NK) : (1.0f / NQ);
  float* ab = seg ? abk : abq;
  float s = st[2 * j], s2 = st[2 * j + 1];
  float m = s * invN;
  float v = fmaxf(s2 * invN - m * m, 0.f);
  float a = g[j] * rsqrtf(v + 1e-5f);
  ab[2 * j] = a;
  ab[2 * j + 1] = bt[j] - a * m;
}

// ---------------- fold BN into weights: q AND k in one pass ---------------
// Reads W once, writes both wq/wk. For layers >=1 computes ab INLINE from
// the previous gemm's stats. Blocks 0,1 zero the CURRENT layer's stat
// buffers (ping-pong pair, distinct from the stats being read).
__global__ __launch_bounds__(256) void fold_w2(
    const float* __restrict__ W, const float* __restrict__ b,
    const float* __restrict__ abq, const float* __restrict__ abk,   // lyr 0
    const float* __restrict__ stq, const float* __restrict__ stk,   // lyr >=1
    const float* __restrict__ g, const float* __restrict__ bt,      // prev BN
    int K,
    unsigned short* __restrict__ Woq, unsigned short* __restrict__ Wok,
    float* __restrict__ boq, float* __restrict__ bok,
    float* __restrict__ statzq, float* __restrict__ statzk, int M,
    int useStats) {
  int j = blockIdx.x;
  int t = threadIdx.x;
  if (j == 0) for (int i = t; i < 2 * M; i += 256) statzq[i] = 0.f;
  if (j == 1) for (int i = t; i < 2 * M; i += 256) statzk[i] = 0.f;
  const float* Wr = W + (size_t)j * K;
  unsigned short* Wq = Woq + (size_t)j * K;
  unsigned short* Wk = Wok + (size_t)j * K;
  float sq = 0.f, sk = 0.f;
  for (int k = t; k < K; k += 256) {
    float w = Wr[k];
    float aq, bq_, ak, bk_;
    if (useStats) {
      float s = stq[2 * k], s2 = stq[2 * k + 1];
      float m = s * (1.0f / NQ);
      float v = fmaxf(s2 * (1.0f / NQ) - m * m, 0.f);
      aq = g[k] * rsqrtf(v + 1e-5f);
      bq_ = bt[k] - aq * m;
      s = stk[2 * k]; s2 = stk[2 * k + 1];
      m = s * (1.0f / NK);
      v = fmaxf(s2 * (1.0f / NK) - m * m, 0.f);
      ak = g[k] * rsqrtf(v + 1e-5f);
      bk_ = bt[k] - ak * m;
    } else {
      aq = abq[2 * k]; bq_ = abq[2 * k + 1];
      ak = abk[2 * k]; bk_ = abk[2 * k + 1];
    }
    Wq[k] = f2bf(aq * w);
    Wk[k] = f2bf(ak * w);
    sq += bq_ * w;
    sk += bk_ * w;
  }
  __shared__ float redq[4], redk[4];
#pragma unroll
  for (int off = 32; off; off >>= 1) {
    sq += __shfl_down(sq, off, 64);
    sk += __shfl_down(sk, off, 64);
  }
  if ((t & 63) == 0) { redq[t >> 6] = sq; redk[t >> 6] = sk; }
  __syncthreads();
  if (t == 0) {
    boq[j] = b[j] + redq[0] + redq[1] + redq[2] + redq[3];
    bok[j] = b[j] + redk[0] + redk[1] + redk[2] + redk[3];
  }
}

// ---------------- merged q/k MFMA GEMM, BK=32, 4-buffer (R4 schedule) -----
// XCD row-clustering swizzle (R13, kept): each XCD owns whole A-row-tiles.
__global__ __launch_bounds__(256) void gemm_v8(
    const unsigned short* __restrict__ A,
    const unsigned short* __restrict__ Wq, const unsigned short* __restrict__ Wk,
    const float* __restrict__ bq, const float* __restrict__ bk,
    unsigned short* __restrict__ C,
    float* __restrict__ stq, float* __restrict__ stk, int M, int K) {
  __shared__ unsigned short As[4][128 * 32];
  __shared__ unsigned short Ws[4][128 * 32];
  int tid = threadIdx.x;
  int l = tid & 63, w = tid >> 6;
  int nx = gridDim.x;
  int lin = blockIdx.y * nx + blockIdx.x;
  int xcd = lin & 7, j = lin >> 3;
  int rowB = (j / nx) * 8 + xcd;     // each XCD: rows {xcd, xcd+8, ...}
  int colB = j % nx;
  int rowBase = rowB * 128, colBase = colB * 128;
  int seg = rowBase >= NQ;
  const unsigned short* W = seg ? Wk : Wq;
  const float* bias = seg ? bk : bq;
  float* st = seg ? stk : stq;
  int rowOff = (w >> 1) * 64, colOff = (w & 1) * 64;
  int fr = l & 15, fc = l >> 4;

  const unsigned short* Ag[2];
  const unsigned short* Wg[2];
  int slot[2];
#pragma unroll
  for (int jj = 0; jj < 2; ++jj) {
    int i = tid + jj * 256;
    int r = i >> 2, c = (i & 3) ^ (r & 3);
    slot[jj] = i * 8;
    Ag[jj] = A + (size_t)(rowBase + r) * K + c * 8;
    Wg[jj] = W + (size_t)(colBase + r) * K + c * 8;
  }
  auto stage = [&](int s, int bb) {
    int ko = s * 32;
#pragma unroll
    for (int jj = 0; jj < 2; ++jj) {
      gload_lds16(Ag[jj] + ko, &As[bb][0] + slot[jj]);
      gload_lds16(Wg[jj] + ko, &Ws[bb][0] + slot[jj]);
    }
  };

  f32x4 acc[4][4];
#pragma unroll
  for (int m = 0; m < 4; ++m)
#pragma unroll
    for (int n = 0; n < 4; ++n) acc[m][n] = (f32x4){0.f, 0.f, 0.f, 0.f};

  int NS = K >> 5;   // 16 or 32 slices
  stage(0, 0);
  stage(1, 1);
  stage(2, 2);
  for (int s = 0; s < NS; ++s) {
    if (s + 2 < NS) {
      asm volatile("s_waitcnt vmcnt(8)" ::: "memory");
    } else if (s + 1 < NS) {
      asm volatile("s_waitcnt vmcnt(4)" ::: "memory");
    } else {
      asm volatile("s_waitcnt vmcnt(0)" ::: "memory");
    }
    __builtin_amdgcn_s_barrier();
    __builtin_amdgcn_sched_barrier(0);
    int b = s & 3;
    bf16x8 av[4], bv[4];
#pragma unroll
    for (int m = 0; m < 4; ++m) {
      int row = rowOff + m * 16 + fr;
      int p = fc ^ (row & 3);
      av[m] = *(const bf16x8*)((const char*)&As[b][0] + row * 64 + p * 16);
    }
#pragma unroll
    for (int n = 0; n < 4; ++n) {
      int row = colOff + n * 16 + fr;
      int p = fc ^ (row & 3);
      bv[n] = *(const bf16x8*)((const char*)&Ws[b][0] + row * 64 + p * 16);
    }
    if (s + 3 < NS) stage(s + 3, (s + 3) & 3);
#pragma unroll
    for (int m = 0; m < 4; ++m)
#pragma unroll
      for (int n = 0; n < 4; ++n)
        acc[m][n] = __builtin_amdgcn_mfma_f32_16x16x32_bf16(av[m], bv[n], acc[m][n], 0, 0, 0);
  }

  float ts1[4] = {0.f, 0.f, 0.f, 0.f};
  float ts2[4] = {0.f, 0.f, 0.f, 0.f};
#pragma unroll
  for (int m = 0; m < 4; ++m) {
#pragma unroll
    for (int r = 0; r < 4; ++r) {
      size_t row = rowBase + rowOff + m * 16 + fc * 4 + r;
      unsigned short* Crow = C + row * M;
#pragma unroll
      for (int n = 0; n < 4; ++n) {
        int col = colBase + colOff + n * 16 + fr;
        float val = fast_tanh(acc[m][n][r] + bias[col]);
        Crow[col] = f2bf(val);
        ts1[n] += val;
        ts2[n] += val * val;
      }
    }
  }
#pragma unroll
  for (int n = 0; n < 4; ++n) {
    float s1 = ts1[n], s2 = ts2[n];
    s1 += __shfl_xor(s1, 16, 64); s1 += __shfl_xor(s1, 32, 64);
    s2 += __shfl_xor(s2, 16, 64); s2 += __shfl_xor(s2, 32, 64);
    if (fc == 0) {
      int col = colBase + colOff + n * 16 + fr;
      atomicAdd(&st[2 * col], s1);
      atomicAdd(&st[2 * col + 1], s2);
    }
  }
}

// ---------------- final BN apply + row norms, q and k in ONE dispatch -----
__global__ __launch_bounds__(256) void bn_final2(
    unsigned short* __restrict__ F, const float* __restrict__ abq,
    const float* __restrict__ abk, float* __restrict__ norms) {
  int w = threadIdx.x >> 6, l = threadIdx.x & 63;
  int row = blockIdx.x * 4 + w;
  const float* ab = (row < NQ) ? abq : abk;
  unsigned short* p = F + (size_t)row * 512 + l * 8;
  uint4 v = *(const uint4*)p;
  int j0 = l * 8;
  float f[8];
  upk(v.x, f[0], f[1]); upk(v.y, f[2], f[3]);
  upk(v.z, f[4], f[5]); upk(v.w, f[6], f[7]);
  float s = 0.f;
  unsigned pk[4];
#pragma unroll
  for (int e = 0; e < 8; e += 2) {
    float a0 = ab[2 * (j0 + e)] * f[e] + ab[2 * (j0 + e) + 1];
    float a1 = ab[2 * (j0 + e + 1)] * f[e + 1] + ab[2 * (j0 + e + 1) + 1];
    s += a0 * a0 + a1 * a1;
    pk[e >> 1] = (unsigned)f2bf(a0) | ((unsigned)f2bf(a1) << 16);
  }
  *(uint4*)p = make_uint4(pk[0], pk[1], pk[2], pk[3]);
#pragma unroll
  for (int off = 32; off; off >>= 1) s += __shfl_down(s, off, 64);
  if (l == 0) norms[row] = s;
}

// ---------------- OHE^T scatter: oheT[cls][key] = 1.0bf ----------------
__global__ __launch_bounds__(256) void scatter_ohe(
    const int* __restrict__ yn, unsigned short* __restrict__ oheT) {
  int k = blockIdx.x * 256 + threadIdx.x;
  if (k < NK) oheT[(size_t)yn[k] * NK + k] = 0x3F80;   // bf16 1.0
}

// ---------------- distance + exp + class-sum via double MFMA ---------------
// R15's proven core (260us, DCH=4): byte-identical.
__global__ __launch_bounds__(512, 2) void dist_v5(
    const unsigned short* __restrict__ F,   // [20480,512]; Q rows 0.., K rows 4096..
    const float* __restrict__ norms,        // [20480]
    const unsigned short* __restrict__ oheT,// [PCLS][NK] bf16
    float* __restrict__ part) {             // [NQ][DCH][PCLS]
  __shared__ unsigned short kbuf[3][128 * 64];   // 3 x 16KB, XOR-swizzled rows
  __shared__ unsigned short Qs[8 * 64 * 64];     // 64KB Q tile, 8 subtiles, swz
  __shared__ unsigned short Ps[64][136];         // P tile [q][key], pad 8
  __shared__ float k2s[4096];                    // 16KB: chunk key norms
  int tid = threadIdx.x;
  int l = tid & 63, w = tid >> 6;
  int qBase = blockIdx.x * 64;
  int kBase0 = blockIdx.y * 4096;
  int mg = w & 1, ng = w >> 1;          // main: q-half, key-quarter
  int qtw = w & 3, cth = w >> 2;        // mini: q-tile, cls-half
  int fr = l & 15, fc = l >> 4;

  for (int i = tid; i < 4096; i += 512) k2s[i] = norms[NQ + kBase0 + i];
  float q2r0 = norms[qBase + mg * 32 + fr];
  float q2r1 = norms[qBase + mg * 32 + 16 + fr];
  __builtin_amdgcn_sched_barrier(0);

  // Q tile -> LDS, 8 subtiles of [64 rows][64 cols], 128B row stride.
#pragma unroll
  for (int j = 0; j < 8; ++j) {
    int i = tid + j * 512;
    int ss = i >> 9;
    int row = (i >> 3) & 63;
    int c = (i & 7) ^ (row & 7);
    gload_lds16(F + (size_t)(qBase + row) * 512 + ss * 64 + c * 8, Qs + i * 8);
  }

  int i0 = tid, i1 = tid + 512;
  int r0 = i0 >> 3, c0 = (i0 & 7) ^ (r0 & 7);
  int r1 = i1 >> 3, c1 = (i1 & 7) ^ (r1 & 7);
  auto stage = [&](int slice, int bb) {   // slice 0..255 over the 4096-key chunk
    int kRow = kBase0 + (slice >> 3) * 128;
    int ko = (slice & 7) * 64;
    gload_lds16(F + (size_t)(NQ + kRow + r0) * 512 + ko + c0 * 8,
                &kbuf[bb][0] + i0 * 8);
    gload_lds16(F + (size_t)(NQ + kRow + r1) * 512 + ko + c1 * 8,
                &kbuf[bb][0] + i1 * 8);
  };

  f32x4 accC[4];
#pragma unroll
  for (int c = 0; c < 4; ++c) accC[c] = (f32x4){0.f, 0.f, 0.f, 0.f};

  stage(0, 0);
  stage(1, 1);
  asm volatile("s_waitcnt lgkmcnt(0)" ::: "memory");  // k2s ds_writes done

  for (int kt = 0; kt < 32; ++kt) {
    f32x4 acc[2][2];   // [key-16-tile][q-tile]
#pragma unroll
    for (int t2 = 0; t2 < 2; ++t2)
#pragma unroll
      for (int qt = 0; qt < 2; ++qt) acc[t2][qt] = (f32x4){0.f, 0.f, 0.f, 0.f};
    bf16x8 ob[4][4];   // per-kt OHE fragments, prefetched at s==0
#pragma unroll
    for (int kc = 0; kc < 4; ++kc)
#pragma unroll
      for (int c = 0; c < 4; ++c) ob[kc][c] = (bf16x8){0, 0, 0, 0, 0, 0, 0, 0};
#pragma unroll
    for (int s = 0; s < 8; ++s) {
      int slice = kt * 8 + s;
      // Queue model (issue order pinned by sched_barriers):
      //   s==0: [st(s)] [st(s+1)] (+Q(8) at kt==0)       -> vmcnt(2)
      //   s==1: [st(s)] [st(s+1)] [ob(16)]               -> vmcnt(18)
      //   s==2: [st(s)] [ob(16)] [st(s+1)]               -> vmcnt(18)
      //   s>=3: [ob?(done)] [st(s)] [st(s+1)]            -> vmcnt(2)
      //   slice==255: only [st(255)] outstanding         -> vmcnt(0)
      if (slice == 255) {
        asm volatile("s_waitcnt vmcnt(0)" ::: "memory");
      } else if (s == 1 || s == 2) {
        asm volatile("s_waitcnt vmcnt(18)" ::: "memory");
      } else {
        asm volatile("s_waitcnt vmcnt(2)" ::: "memory");
      }
      __builtin_amdgcn_s_barrier();
      __builtin_amdgcn_sched_barrier(0);  // pin issues below the barrier
      int b = slice % 3;
      bf16x8 kv[2][2];
#pragma unroll
      for (int kc = 0; kc < 2; ++kc)
#pragma unroll
        for (int t2 = 0; t2 < 2; ++t2) {
          int row = ng * 32 + t2 * 16 + fr;
          int sl = (kc * 4 + fc) ^ (row & 7);
          kv[kc][t2] = *(const bf16x8*)((const char*)&kbuf[b][0] + row * 128 + sl * 16);
        }
      bf16x8 avx[2][2];  // [kc][qt] Q fragments from LDS subtile s
#pragma unroll
      for (int kc = 0; kc < 2; ++kc)
#pragma unroll
        for (int qt = 0; qt < 2; ++qt) {
          int row = mg * 32 + qt * 16 + fr;
          int sl = (kc * 4 + fc) ^ (fr & 7);
          avx[kc][qt] = *(const bf16x8*)((const char*)Qs + s * 8192 + row * 128 + sl * 16);
        }
      if (slice + 2 < 256) stage(slice + 2, (slice + 2) % 3);
      if (s == 0) {
        __builtin_amdgcn_sched_barrier(0);  // keep ob issue after stage pair
#pragma unroll
        for (int kc = 0; kc < 4; ++kc)
#pragma unroll
          for (int c = 0; c < 4; ++c) {
            int ctg = cth * 4 + c;
            if (ctg < 7)
              ob[kc][c] = *(const bf16x8*)(
                  oheT + (size_t)(ctg * 16 + fr) * NK + kBase0 + kt * 128 + kc * 32 + fc * 8);
          }
        __builtin_amdgcn_sched_barrier(0);
      }
#pragma unroll
      for (int kc = 0; kc < 2; ++kc)
#pragma unroll
        for (int t2 = 0; t2 < 2; ++t2)
#pragma unroll
          for (int qt = 0; qt < 2; ++qt)
            acc[t2][qt] = __builtin_amdgcn_mfma_f32_16x16x32_bf16(
                kv[kc][t2], avx[kc][qt], acc[t2][qt], 0, 0, 0);
    }
    // ---- epilogue: p = exp(-dist) -> bf16 -> Ps[q][key] ----
#pragma unroll
    for (int t2 = 0; t2 < 2; ++t2) {
      float k2v[4];
#pragma unroll
      for (int r = 0; r < 4; ++r)
        k2v[r] = k2s[kt * 128 + ng * 32 + t2 * 16 + fc * 4 + r];
#pragma unroll
      for (int qt = 0; qt < 2; ++qt) {
        int q = mg * 32 + qt * 16 + fr;
        float q2 = qt ? q2r1 : q2r0;
        float pv[4];
#pragma unroll
        for (int r = 0; r < 4; ++r) {
          float d2 = q2 + k2v[r] - 2.f * acc[t2][qt][r];
          pv[r] = __expf(-sqrtf(fmaxf(d2, 0.f)));
        }
        unsigned lo = (unsigned)f2bf(pv[0]) | ((unsigned)f2bf(pv[1]) << 16);
        unsigned hi = (unsigned)f2bf(pv[2]) | ((unsigned)f2bf(pv[3]) << 16);
        *(uint2*)(&Ps[q][ng * 32 + t2 * 16 + fc * 4]) = make_uint2(lo, hi);
      }
    }
    asm volatile("s_waitcnt lgkmcnt(0)" ::: "memory");
    __builtin_amdgcn_s_barrier();
    __builtin_amdgcn_sched_barrier(0);
    // ---- mini-GEMM: accC[q][cls] += P[q][k] * OHE[k][cls] (ob pre-loaded) --
#pragma unroll
    for (int kc = 0; kc < 4; ++kc) {
      bf16x8 pa = *(const bf16x8*)(&Ps[qtw * 16 + fr][kc * 32 + fc * 8]);
#pragma unroll
      for (int c = 0; c < 4; ++c) {
        int ctg = cth * 4 + c;
        if (ctg < 7)
          accC[c] = __builtin_amdgcn_mfma_f32_16x16x32_bf16(pa, ob[kc][c], accC[c], 0, 0, 0);
      }
    }
  }
  // ---- write per-chunk class sums ----
#pragma unroll
  for (int c = 0; c < 4; ++c) {
    int ctg = cth * 4 + c;
    if (ctg < 7) {
#pragma unroll
      for (int r = 0; r < 4; ++r) {
        int q = qBase + qtw * 16 + fc * 4 + r;
        part[((size_t)q * DCH + blockIdx.y) * PCLS + ctg * 16 + fr] = accC[c][r];
      }
    }
  }
}

// ---------------- combine partials -> clipped scores ----------------
__global__ __launch_bounds__(128) void combine_out(
    const float* __restrict__ part, float* __restrict__ outp) {
  int q = blockIdx.x;
  int t = threadIdx.x;
  float num = 0.f;
  if (t < NCLS) {
#pragma unroll
    for (int ch = 0; ch < DCH; ++ch)
      num += part[((size_t)q * DCH + ch) * PCLS + t];
  }
  __shared__ float sn[128];
  sn[t] = (t < NCLS) ? num : 0.f;
  __syncthreads();
#pragma unroll
  for (int off = 64; off; off >>= 1) {
    if (t < off) sn[t] += sn[t + off];
    __syncthreads();
  }
  float L = sn[0];
  if (t < NCLS) outp[(size_t)q * NCLS + t] = fminf(fmaxf(num / L, 0.f), 1.f);
}

// ---------------- host orchestration ----------------
extern "C" void kernel_launch(void* const* d_in, const int* in_sizes, int n_in,
                              void* d_out, int out_size, void* d_ws, size_t ws_size,
                              hipStream_t stream) {
  (void)in_sizes; (void)n_in; (void)out_size; (void)ws_size;
  const float* x   = (const float*)d_in[0];
  const float* xn  = (const float*)d_in[1];
  const int*   yn  = (const int*)d_in[2];
  const float* ing = (const float*)d_in[3];
  const float* inb = (const float*)d_in[4];
  const float* Wl[3]  = {(const float*)d_in[5], (const float*)d_in[9],  (const float*)d_in[13]};
  const float* bl[3]  = {(const float*)d_in[6], (const float*)d_in[10], (const float*)d_in[14]};
  const float* gl[3]  = {(const float*)d_in[7], (const float*)d_in[11], (const float*)d_in[15]};
  const float* btl[3] = {(const float*)d_in[8], (const float*)d_in[12], (const float*)d_in[16]};
  float* outp = (float*)d_out;

  unsigned short* featA = (unsigned short*)d_ws;                 // 20480*1024 bf16
  unsigned short* featB = featA + (size_t)NROWS * 1024;
  unsigned short* wq  = featB + (size_t)NROWS * 1024;            // 1024*1024 bf16
  unsigned short* wk  = wq + (size_t)1024 * 1024;                // 1024*1024 bf16
  unsigned short* ohe = wk + (size_t)1024 * 1024;                // PCLS*NK bf16
  float* spart = (float*)(ohe + (size_t)PCLS * NK);              // 2*64*2*512
  float* abq   = spart + 2 * 64 * 2 * 512;                       // 2048
  float* abk   = abq + 2048;                                     // 2048
  float* stAq  = abk + 2048;                                     // 2048
  float* stAk  = stAq + 2048;                                    // 2048
  float* stBq  = stAk + 2048;                                    // 2048
  float* stBk  = stBq + 2048;                                    // 2048
  float* bpq   = stBk + 2048;                                    // 1024
  float* bpk   = bpq + 1024;                                     // 1024
  float* norms = bpk + 1024;                                     // 20480
  float* part  = norms + NROWS;                                  // NQ*DCH*PCLS

  // input BN stats for both segments (2 dispatches)
  colstats2<<<dim3(2, 64, 2), 256, 0, stream>>>(x, xn, spart);
  finish_ab2<<<dim3(2, 2), 256, 0, stream>>>(spart, ing, inb, abq, abk);

  // raw inputs -> bf16 (1 dispatch)
  conv2_bf16<<<2048, 256, 0, stream>>>(x, xn, featA);

  // one-hot transpose for the class mini-GEMM
  hipMemsetAsync(ohe, 0, (size_t)PCLS * NK * sizeof(unsigned short), stream);
  scatter_ohe<<<NK / 256, 256, 0, stream>>>(yn, ohe);

  int dims[4] = {512, 1024, 1024, 512};
  unsigned short *src = featA, *dst = featB;
  for (int lyr = 0; lyr < 3; ++lyr) {
    int K = dims[lyr], M = dims[lyr + 1];
    // ping-pong stat buffers: layer lyr accumulates into cur, fold reads prev
    float* curQ = (lyr & 1) ? stBq : stAq;
    float* curK = (lyr & 1) ? stBk : stAk;
    float* prevQ = (lyr & 1) ? stAq : stBq;
    float* prevK = (lyr & 1) ? stAk : stBk;
    // fold q+k in one pass; for lyr>=1 computes ab inline from prev stats
    fold_w2<<<M, 256, 0, stream>>>(
        Wl[lyr], bl[lyr], abq, abk, prevQ, prevK,
        lyr ? gl[lyr - 1] : ing, lyr ? btl[lyr - 1] : inb,
        K, wq, wk, bpq, bpk, curQ, curK, M, lyr > 0);
    // merged q+k GEMM: rows 0..NQ-1 use wq/bpq/statq, rest wk/bpk/statk
    gemm_v8<<<dim3(M / 128, NROWS / 128), 256, 0, stream>>>(
        src, wq, wk, bpq, bpk, dst, curQ, curK, M, K);
    unsigned short* t = src; src = dst; dst = t;
  }
  // final ab (layer-2 stats live in the lyr=2 'cur' pair = stA)
  ab_from_stats2<<<dim3(2, 2), 256, 0, stream>>>(
      stAq, stAk, gl[2], btl[2], abq, abk, 512);
  // final BN + row norms for all 20480 rows (1 dispatch)
  bn_final2<<<NROWS / 4, 256, 0, stream>>>(src, abq, abk, norms);

  dist_v5<<<dim3(NQ / 64, DCH), 512, 0, stream>>>(src, norms, ohe, part);
  combine_out<<<NQ, 128, 0, stream>>>(part, outp);
}